// Round 2
// baseline (643.407 us; speedup 1.0000x reference)
//
#include <hip/hip_runtime.h>

// ws layout:
//   [0, K*4)                      : uint32 hist[K]          (merged result; fallback path atomics here)
//   [K*4, K*4 + R*K*4)            : uint32 replicas[R][K]   (fast path, R=8, one per XCD)
//   [align256(end), +16)          : double accums[2]  {sum_smoothed, bits_sum}

__global__ void zero_kernel(unsigned* __restrict__ buf, long long nwords,
                            double* __restrict__ accums) {
    long long i = (long long)blockIdx.x * blockDim.x + threadIdx.x;
    long long stride = (long long)gridDim.x * blockDim.x;
    for (long long k = i; k < nwords; k += stride) buf[k] = 0u;
    if (i == 0) { accums[0] = 0.0; accums[1] = 0.0; }
}

template <bool REPL>
__global__ void hist_kernel(const int* __restrict__ idx, long long n,
                            unsigned* __restrict__ hist_base, int K) {
    unsigned* h = hist_base;
    if constexpr (REPL) {
        unsigned xcc;
        asm volatile("s_getreg_b32 %0, hwreg(HW_REG_XCC_ID)" : "=s"(xcc));
        h = hist_base + (size_t)(xcc & 7u) * (size_t)K;
    }
    long long tid = (long long)blockIdx.x * blockDim.x + threadIdx.x;
    long long nthreads = (long long)gridDim.x * blockDim.x;
    long long n4 = n & ~3LL;
    for (long long i = tid * 4; i < n4; i += nthreads * 4) {
        int4 v = *reinterpret_cast<const int4*>(idx + i);
        if constexpr (REPL) {
            __hip_atomic_fetch_add(&h[v.x], 1u, __ATOMIC_RELAXED, __HIP_MEMORY_SCOPE_WORKGROUP);
            __hip_atomic_fetch_add(&h[v.y], 1u, __ATOMIC_RELAXED, __HIP_MEMORY_SCOPE_WORKGROUP);
            __hip_atomic_fetch_add(&h[v.z], 1u, __ATOMIC_RELAXED, __HIP_MEMORY_SCOPE_WORKGROUP);
            __hip_atomic_fetch_add(&h[v.w], 1u, __ATOMIC_RELAXED, __HIP_MEMORY_SCOPE_WORKGROUP);
        } else {
            atomicAdd(&h[v.x], 1u);
            atomicAdd(&h[v.y], 1u);
            atomicAdd(&h[v.z], 1u);
            atomicAdd(&h[v.w], 1u);
        }
    }
    long long rem = n - n4;
    if (tid < rem) {
        int v = idx[n4 + tid];
        if constexpr (REPL)
            __hip_atomic_fetch_add(&h[v], 1u, __ATOMIC_RELAXED, __HIP_MEMORY_SCOPE_WORKGROUP);
        else
            atomicAdd(&h[v], 1u);
    }
}

__device__ __forceinline__ double block_reduce_double(double v) {
    #pragma unroll
    for (int off = 32; off > 0; off >>= 1) v += __shfl_down(v, off, 64);
    __shared__ double ws_[16];
    int lane = threadIdx.x & 63;
    int wid  = threadIdx.x >> 6;
    if (lane == 0) ws_[wid] = v;
    __syncthreads();
    double t = 0.0;
    if (threadIdx.x == 0) {
        int nw = (blockDim.x + 63) >> 6;
        for (int w = 0; w < nw; ++w) t += ws_[w];
    }
    return t;  // valid only on thread 0
}

// Merge R replicas into hist[] and accumulate sum of smoothed counts.
// In fallback mode call with reps == hist, R == 1 (self-copy is race-free).
__global__ void merge_sum_kernel(const unsigned* __restrict__ reps, int R, int K,
                                 const float* __restrict__ sc,
                                 unsigned* __restrict__ hist,
                                 double* __restrict__ accums) {
    int i = blockIdx.x * blockDim.x + threadIdx.x;
    int stride = gridDim.x * blockDim.x;
    double s = 0.0;
    for (int k = i; k < K; k += stride) {
        unsigned h = 0;
        for (int r = 0; r < R; ++r) h += reps[(size_t)r * K + k];
        hist[k] = h;
        s += (double)sc[k] + (double)h + 1e-8;
    }
    double t = block_reduce_double(s);
    if (threadIdx.x == 0) atomicAdd(&accums[0], t);
}

__global__ void bits_kernel(const float* __restrict__ sc, const unsigned* __restrict__ hist,
                            int K, double* __restrict__ accums) {
    double inv_sum = 1.0 / accums[0];
    int i = blockIdx.x * blockDim.x + threadIdx.x;
    int stride = gridDim.x * blockDim.x;
    double b = 0.0;
    for (int k = i; k < K; k += stride) {
        unsigned h = hist[k];
        if (h) {
            double smoothed = (double)sc[k] + (double)h + 1e-8;
            float p = (float)(smoothed * inv_sum);
            p = fmaxf(p, 1e-10f);
            b += (double)h * (double)(-log2f(p));
        }
    }
    double t = block_reduce_double(b);
    if (threadIdx.x == 0) atomicAdd(&accums[1], t);
}

__global__ void finalize_kernel(const double* __restrict__ accums, float* __restrict__ out,
                                long long n) {
    if (threadIdx.x == 0 && blockIdx.x == 0)
        out[0] = (float)(accums[1] / (double)n);
}

extern "C" void kernel_launch(void* const* d_in, const int* in_sizes, int n_in,
                              void* d_out, int out_size, void* d_ws, size_t ws_size,
                              hipStream_t stream) {
    const int*   indices = (const int*)d_in[0];
    const float* sc      = (const float*)d_in[1];
    long long n = (long long)in_sizes[0];   // B*T = 16,777,216
    int K = in_sizes[1];                    // 65536

    const int R = 8;  // one replica per XCD
    size_t hist_bytes = (size_t)K * 4;
    size_t fast_need  = hist_bytes * (1 + R) + 256 + 16;
    bool fast = ws_size >= fast_need;

    unsigned* hist = (unsigned*)d_ws;
    unsigned* reps = fast ? hist + K : hist;
    size_t end_off = fast ? hist_bytes * (1 + R) : hist_bytes;
    size_t acc_off = (end_off + 255) & ~(size_t)255;
    double* accums = (double*)((char*)d_ws + acc_off);
    float* out = (float*)d_out;

    long long zero_words = fast ? (long long)K * (1 + R) : (long long)K;
    zero_kernel<<<1024, 256, 0, stream>>>(hist, zero_words, accums);

    if (fast)
        hist_kernel<true><<<2048, 256, 0, stream>>>(indices, n, reps, K);
    else
        hist_kernel<false><<<2048, 256, 0, stream>>>(indices, n, hist, K);

    merge_sum_kernel<<<256, 256, 0, stream>>>(reps, fast ? R : 1, K, sc, hist, accums);
    bits_kernel<<<256, 256, 0, stream>>>(sc, hist, K, accums);
    finalize_kernel<<<1, 64, 0, stream>>>(accums, out, n);
}

// Round 3
// 54.718 us; speedup vs baseline: 11.7586x; 11.7586x over previous
//
#include <hip/hip_runtime.h>

// Fast path ws layout:
//   [0, NB*W*4)        : uint32 partials[NB][W]  (W = K/2 packed uint16-pair words)
//   [NB*W*4, +K*4)     : uint32 hist[K] (merged)
//   [align256, +16)    : double accums[2] {sum_smoothed, bits_sum}
// Fallback (tiny ws): global-atomic hist as in round 1.

__global__ void zero_kernel(unsigned* __restrict__ buf, long long nwords,
                            double* __restrict__ accums) {
    long long i = (long long)blockIdx.x * blockDim.x + threadIdx.x;
    long long stride = (long long)gridDim.x * blockDim.x;
    for (long long k = i; k < nwords; k += stride) buf[k] = 0u;
    if (i == 0) { accums[0] = 0.0; accums[1] = 0.0; }
}

// ---- fast path: per-block LDS histogram (packed uint16 pairs), no global atomics ----
__global__ __launch_bounds__(1024) void lds_hist_kernel(const int* __restrict__ idx, long long n,
                                                        unsigned* __restrict__ partials,
                                                        int K, int nb) {
    __shared__ unsigned lds[32768];  // 128 KB: K/2 packed uint16 pairs
    const int W = K >> 1;
    for (int w = threadIdx.x; w < W; w += blockDim.x) lds[w] = 0u;
    __syncthreads();

    long long per = (((n + nb - 1) / nb) + 3) & ~3LL;      // per-block slice, multiple of 4
    long long start = (long long)blockIdx.x * per;
    long long end = start + per; if (end > n) end = n;
    if (start < end) {
        long long vend = start + ((end - start) & ~3LL);
        for (long long i = start + (long long)threadIdx.x * 4; i < vend;
             i += (long long)blockDim.x * 4) {
            int4 v = *reinterpret_cast<const int4*>(idx + i);
            atomicAdd(&lds[((unsigned)v.x) >> 1], 1u << ((v.x & 1) << 4));
            atomicAdd(&lds[((unsigned)v.y) >> 1], 1u << ((v.y & 1) << 4));
            atomicAdd(&lds[((unsigned)v.z) >> 1], 1u << ((v.z & 1) << 4));
            atomicAdd(&lds[((unsigned)v.w) >> 1], 1u << ((v.w & 1) << 4));
        }
        for (long long i = vend + threadIdx.x; i < end; i += blockDim.x) {
            int v = idx[i];
            atomicAdd(&lds[((unsigned)v) >> 1], 1u << ((v & 1) << 4));
        }
    }
    __syncthreads();
    unsigned* out = partials + (size_t)blockIdx.x * W;
    for (int w = threadIdx.x; w < W; w += blockDim.x) out[w] = lds[w];
}

__device__ __forceinline__ double block_reduce_double(double v) {
    #pragma unroll
    for (int off = 32; off > 0; off >>= 1) v += __shfl_down(v, off, 64);
    __shared__ double ws_[16];
    int lane = threadIdx.x & 63;
    int wid  = threadIdx.x >> 6;
    if (lane == 0) ws_[wid] = v;
    __syncthreads();
    double t = 0.0;
    if (threadIdx.x == 0) {
        int nw = (blockDim.x + 63) >> 6;
        for (int w = 0; w < nw; ++w) t += ws_[w];
    }
    return t;  // valid only on thread 0
}

// Merge nb packed partials -> hist[K]; fused smoothed-sum reduction.
__global__ void merge_sum_kernel(const unsigned* __restrict__ partials, int nb, int K,
                                 const float* __restrict__ sc,
                                 unsigned* __restrict__ hist,
                                 double* __restrict__ accums) {
    const int W = K >> 1;
    int stride = gridDim.x * blockDim.x;
    double s = 0.0;
    for (int w = blockIdx.x * blockDim.x + threadIdx.x; w < W; w += stride) {
        unsigned lo = 0, hi = 0;
        #pragma unroll 4
        for (int b = 0; b < nb; ++b) {
            unsigned v = partials[(size_t)b * W + w];
            lo += v & 0xFFFFu;
            hi += v >> 16;
        }
        hist[2 * w]     = lo;
        hist[2 * w + 1] = hi;
        s += (double)sc[2 * w]     + (double)lo + 1e-8;
        s += (double)sc[2 * w + 1] + (double)hi + 1e-8;
    }
    double t = block_reduce_double(s);
    if (threadIdx.x == 0) atomicAdd(&accums[0], t);
}

// ---- fallback path (tiny ws): global atomics as in round 1 ----
__global__ void ghist_kernel(const int* __restrict__ idx, long long n,
                             unsigned* __restrict__ hist) {
    long long tid = (long long)blockIdx.x * blockDim.x + threadIdx.x;
    long long nthreads = (long long)gridDim.x * blockDim.x;
    long long n4 = n & ~3LL;
    for (long long i = tid * 4; i < n4; i += nthreads * 4) {
        int4 v = *reinterpret_cast<const int4*>(idx + i);
        atomicAdd(&hist[v.x], 1u); atomicAdd(&hist[v.y], 1u);
        atomicAdd(&hist[v.z], 1u); atomicAdd(&hist[v.w], 1u);
    }
    long long rem = n - n4;
    if (tid < rem) atomicAdd(&hist[idx[n4 + tid]], 1u);
}

__global__ void sum_kernel(const float* __restrict__ sc, const unsigned* __restrict__ hist,
                           int K, double* __restrict__ accums) {
    int i = blockIdx.x * blockDim.x + threadIdx.x;
    int stride = gridDim.x * blockDim.x;
    double s = 0.0;
    for (int k = i; k < K; k += stride)
        s += (double)sc[k] + (double)hist[k] + 1e-8;
    double t = block_reduce_double(s);
    if (threadIdx.x == 0) atomicAdd(&accums[0], t);
}

__global__ void bits_kernel(const float* __restrict__ sc, const unsigned* __restrict__ hist,
                            int K, double* __restrict__ accums) {
    double inv_sum = 1.0 / accums[0];
    int i = blockIdx.x * blockDim.x + threadIdx.x;
    int stride = gridDim.x * blockDim.x;
    double b = 0.0;
    for (int k = i; k < K; k += stride) {
        unsigned h = hist[k];
        if (h) {
            double smoothed = (double)sc[k] + (double)h + 1e-8;
            float p = (float)(smoothed * inv_sum);
            p = fmaxf(p, 1e-10f);
            b += (double)h * (double)(-log2f(p));
        }
    }
    double t = block_reduce_double(b);
    if (threadIdx.x == 0) atomicAdd(&accums[1], t);
}

__global__ void finalize_kernel(const double* __restrict__ accums, float* __restrict__ out,
                                long long n) {
    if (threadIdx.x == 0 && blockIdx.x == 0)
        out[0] = (float)(accums[1] / (double)n);
}

extern "C" void kernel_launch(void* const* d_in, const int* in_sizes, int n_in,
                              void* d_out, int out_size, void* d_ws, size_t ws_size,
                              hipStream_t stream) {
    const int*   indices = (const int*)d_in[0];
    const float* sc      = (const float*)d_in[1];
    long long n = (long long)in_sizes[0];   // B*T = 16,777,216
    int K = in_sizes[1];                    // 65536
    float* out = (float*)d_out;

    const size_t W = (size_t)K >> 1;
    // pick largest block count whose partial buffer fits ws
    int nb = 0;
    for (int cand : {256, 128, 64}) {
        size_t need = (size_t)cand * W * 4 + (size_t)K * 4 + 256 + 16;
        if (ws_size >= need) { nb = cand; break; }
    }

    if (nb > 0) {
        unsigned* partials = (unsigned*)d_ws;
        unsigned* hist = partials + (size_t)nb * W;
        size_t acc_off = (((size_t)nb * W * 4 + (size_t)K * 4) + 255) & ~(size_t)255;
        double* accums = (double*)((char*)d_ws + acc_off);

        zero_kernel<<<1, 64, 0, stream>>>((unsigned*)d_ws, 0, accums);  // accums only
        lds_hist_kernel<<<nb, 1024, 0, stream>>>(indices, n, partials, K, nb);
        merge_sum_kernel<<<128, 256, 0, stream>>>(partials, nb, K, sc, hist, accums);
        bits_kernel<<<256, 256, 0, stream>>>(sc, hist, K, accums);
        finalize_kernel<<<1, 64, 0, stream>>>(accums, out, n);
    } else {
        unsigned* hist = (unsigned*)d_ws;
        size_t acc_off = ((size_t)K * 4 + 255) & ~(size_t)255;
        double* accums = (double*)((char*)d_ws + acc_off);

        zero_kernel<<<256, 256, 0, stream>>>(hist, K, accums);
        ghist_kernel<<<2048, 256, 0, stream>>>(indices, n, hist);
        sum_kernel<<<256, 256, 0, stream>>>(sc, hist, K, accums);
        bits_kernel<<<256, 256, 0, stream>>>(sc, hist, K, accums);
        finalize_kernel<<<1, 64, 0, stream>>>(accums, out, n);
    }
}

// Round 5
// 42.013 us; speedup vs baseline: 15.3143x; 1.3024x over previous
//
#include <hip/hip_runtime.h>

typedef int   int4e   __attribute__((ext_vector_type(4)));
typedef unsigned uint4e __attribute__((ext_vector_type(4)));

// Fast path ws layout (K=65536, nb=256):
//   [0, nb*W*4)         : uint32 partials[nb][W]   (W = K/2 packed uint16-pair words)
//   [+K*4)              : uint32 hist[K] (merged)
//   [align256, +24)     : double accums[2] {sum_smoothed, bits_sum}; uint32 counter
// Fallback (tiny ws): global-atomic hist.

// ---- fast path: per-block LDS histogram (packed uint16 pairs) ----
__global__ __launch_bounds__(1024) void lds_hist_kernel(const int* __restrict__ idx, long long n,
                                                        unsigned* __restrict__ partials,
                                                        int K, int nb,
                                                        double* __restrict__ accums) {
    if (blockIdx.x == 0 && threadIdx.x == 0) {
        accums[0] = 0.0; accums[1] = 0.0;
        *reinterpret_cast<unsigned*>(accums + 2) = 0u;   // finalize ticket counter
    }
    __shared__ __align__(16) unsigned lds[32768];  // 128 KB: K/2 packed uint16 pairs
    const int W = K >> 1;
    uint4e* lds4 = reinterpret_cast<uint4e*>(lds);
    const int W4 = W >> 2;
    for (int w = threadIdx.x; w < W4; w += blockDim.x) lds4[w] = (uint4e){0u, 0u, 0u, 0u};
    __syncthreads();

    long long per = (((n + nb - 1) / nb) + 3) & ~3LL;      // per-block slice, multiple of 4
    long long start = (long long)blockIdx.x * per;
    long long end = start + per; if (end > n) end = n;
    if (start < end) {
        long long vend = start + ((end - start) & ~3LL);
        long long step = (long long)blockDim.x * 4;
        long long i = start + (long long)threadIdx.x * 4;
        for (; i + step < vend; i += 2 * step) {
            int4e a = __builtin_nontemporal_load(reinterpret_cast<const int4e*>(idx + i));
            int4e b = __builtin_nontemporal_load(reinterpret_cast<const int4e*>(idx + i + step));
            atomicAdd(&lds[((unsigned)a.x) >> 1], 1u << ((a.x & 1) << 4));
            atomicAdd(&lds[((unsigned)a.y) >> 1], 1u << ((a.y & 1) << 4));
            atomicAdd(&lds[((unsigned)a.z) >> 1], 1u << ((a.z & 1) << 4));
            atomicAdd(&lds[((unsigned)a.w) >> 1], 1u << ((a.w & 1) << 4));
            atomicAdd(&lds[((unsigned)b.x) >> 1], 1u << ((b.x & 1) << 4));
            atomicAdd(&lds[((unsigned)b.y) >> 1], 1u << ((b.y & 1) << 4));
            atomicAdd(&lds[((unsigned)b.z) >> 1], 1u << ((b.z & 1) << 4));
            atomicAdd(&lds[((unsigned)b.w) >> 1], 1u << ((b.w & 1) << 4));
        }
        if (i < vend) {
            int4e a = __builtin_nontemporal_load(reinterpret_cast<const int4e*>(idx + i));
            atomicAdd(&lds[((unsigned)a.x) >> 1], 1u << ((a.x & 1) << 4));
            atomicAdd(&lds[((unsigned)a.y) >> 1], 1u << ((a.y & 1) << 4));
            atomicAdd(&lds[((unsigned)a.z) >> 1], 1u << ((a.z & 1) << 4));
            atomicAdd(&lds[((unsigned)a.w) >> 1], 1u << ((a.w & 1) << 4));
        }
        for (long long t = vend + threadIdx.x; t < end; t += blockDim.x) {
            int v = idx[t];
            atomicAdd(&lds[((unsigned)v) >> 1], 1u << ((v & 1) << 4));
        }
    }
    __syncthreads();
    uint4e* out4 = reinterpret_cast<uint4e*>(partials + (size_t)blockIdx.x * W);
    for (int w = threadIdx.x; w < W4; w += blockDim.x)
        __builtin_nontemporal_store(lds4[w], &out4[w]);
}

// Merge nb=256 packed partials -> hist[K]; fused smoothed-sum reduction.
// Grid: (W/4)/32 blocks x 256 threads. Block covers 32 uint4-columns (= 256 bins).
// Threads: col = t&31, grp = t>>5 (8 row-groups of nb/8 rows each).
__global__ __launch_bounds__(256) void merge_sum_kernel(const uint4e* __restrict__ partials4,
                                                        int nb, int NC4,
                                                        const float* __restrict__ sc,
                                                        unsigned* __restrict__ hist,
                                                        double* __restrict__ accums) {
    const int col = blockIdx.x * 32 + (threadIdx.x & 31);
    const int grp = threadIdx.x >> 5;       // 0..7
    const int rpg = nb >> 3;                // rows per group
    unsigned acc[8] = {0u,0u,0u,0u,0u,0u,0u,0u};
    const uint4e* p = partials4 + (size_t)(grp * rpg) * NC4 + col;
    #pragma unroll 8
    for (int r = 0; r < rpg; ++r) {
        uint4e v = p[(size_t)r * NC4];
        acc[0] += v.x & 0xFFFFu; acc[1] += v.x >> 16;
        acc[2] += v.y & 0xFFFFu; acc[3] += v.y >> 16;
        acc[4] += v.z & 0xFFFFu; acc[5] += v.z >> 16;
        acc[6] += v.w & 0xFFFFu; acc[7] += v.w >> 16;
    }
    __shared__ unsigned red[7][32][8];
    if (grp > 0) {
        #pragma unroll
        for (int j = 0; j < 8; ++j) red[grp - 1][threadIdx.x & 31][j] = acc[j];
    }
    __syncthreads();
    if (grp == 0) {
        const int c = threadIdx.x;  // 0..31 (lanes 0..31 of wave 0)
        #pragma unroll
        for (int g = 0; g < 7; ++g)
            #pragma unroll
            for (int j = 0; j < 8; ++j) acc[j] += red[g][c][j];
        uint4e* h4 = reinterpret_cast<uint4e*>(hist);
        h4[col * 2]     = (uint4e){acc[0], acc[1], acc[2], acc[3]};
        h4[col * 2 + 1] = (uint4e){acc[4], acc[5], acc[6], acc[7]};
        const float4* s4 = reinterpret_cast<const float4*>(sc);
        float4 f0 = s4[col * 2], f1 = s4[col * 2 + 1];
        double s = ((double)f0.x + acc[0] + 1e-8) + ((double)f0.y + acc[1] + 1e-8)
                 + ((double)f0.z + acc[2] + 1e-8) + ((double)f0.w + acc[3] + 1e-8)
                 + ((double)f1.x + acc[4] + 1e-8) + ((double)f1.y + acc[5] + 1e-8)
                 + ((double)f1.z + acc[6] + 1e-8) + ((double)f1.w + acc[7] + 1e-8);
        #pragma unroll
        for (int off = 16; off > 0; off >>= 1) s += __shfl_down(s, off, 64);
        if (threadIdx.x == 0) atomicAdd(&accums[0], s);
    }
}

__device__ __forceinline__ double block_reduce_double(double v) {
    #pragma unroll
    for (int off = 32; off > 0; off >>= 1) v += __shfl_down(v, off, 64);
    __shared__ double ws_[16];
    int lane = threadIdx.x & 63;
    int wid  = threadIdx.x >> 6;
    if (lane == 0) ws_[wid] = v;
    __syncthreads();
    double t = 0.0;
    if (threadIdx.x == 0) {
        int nw = (blockDim.x + 63) >> 6;
        for (int w = 0; w < nw; ++w) t += ws_[w];
    }
    return t;  // valid only on thread 0
}

// bits + last-block finalize (ticket pattern; counter zeroed by lds_hist/zero_kernel).
__global__ void bits_finalize_kernel(const float* __restrict__ sc,
                                     const unsigned* __restrict__ hist, int K,
                                     double* __restrict__ accums,
                                     float* __restrict__ out, long long n) {
    double inv_sum = 1.0 / accums[0];
    int stride4 = gridDim.x * blockDim.x * 4;
    double b = 0.0;
    for (int k = (blockIdx.x * blockDim.x + threadIdx.x) * 4; k + 3 < K; k += stride4) {
        uint4e  h4 = *reinterpret_cast<const uint4e*>(hist + k);
        float4 f4 = *reinterpret_cast<const float4*>(sc + k);
        if (h4.x) { float p = fmaxf((float)(((double)f4.x + h4.x + 1e-8) * inv_sum), 1e-10f); b += (double)h4.x * (double)(-log2f(p)); }
        if (h4.y) { float p = fmaxf((float)(((double)f4.y + h4.y + 1e-8) * inv_sum), 1e-10f); b += (double)h4.y * (double)(-log2f(p)); }
        if (h4.z) { float p = fmaxf((float)(((double)f4.z + h4.z + 1e-8) * inv_sum), 1e-10f); b += (double)h4.z * (double)(-log2f(p)); }
        if (h4.w) { float p = fmaxf((float)(((double)f4.w + h4.w + 1e-8) * inv_sum), 1e-10f); b += (double)h4.w * (double)(-log2f(p)); }
    }
    double t = block_reduce_double(b);
    unsigned* counter = reinterpret_cast<unsigned*>(accums + 2);
    if (threadIdx.x == 0) {
        atomicAdd(&accums[1], t);
        __threadfence();
        unsigned ticket = __hip_atomic_fetch_add(counter, 1u, __ATOMIC_ACQ_REL, __HIP_MEMORY_SCOPE_AGENT);
        if (ticket == (unsigned)(gridDim.x - 1)) {
            double total = __hip_atomic_load(&accums[1], __ATOMIC_SEQ_CST, __HIP_MEMORY_SCOPE_AGENT);
            out[0] = (float)(total / (double)n);
        }
    }
}

// ---- fallback path (tiny ws): global atomics ----
__global__ void zero_kernel(unsigned* __restrict__ buf, long long nwords,
                            double* __restrict__ accums) {
    long long i = (long long)blockIdx.x * blockDim.x + threadIdx.x;
    long long stride = (long long)gridDim.x * blockDim.x;
    for (long long k = i; k < nwords; k += stride) buf[k] = 0u;
    if (i == 0) { accums[0] = 0.0; accums[1] = 0.0; *reinterpret_cast<unsigned*>(accums + 2) = 0u; }
}

__global__ void ghist_kernel(const int* __restrict__ idx, long long n,
                             unsigned* __restrict__ hist) {
    long long tid = (long long)blockIdx.x * blockDim.x + threadIdx.x;
    long long nthreads = (long long)gridDim.x * blockDim.x;
    long long n4 = n & ~3LL;
    for (long long i = tid * 4; i < n4; i += nthreads * 4) {
        int4e v = *reinterpret_cast<const int4e*>(idx + i);
        atomicAdd(&hist[v.x], 1u); atomicAdd(&hist[v.y], 1u);
        atomicAdd(&hist[v.z], 1u); atomicAdd(&hist[v.w], 1u);
    }
    long long rem = n - n4;
    if (tid < rem) atomicAdd(&hist[idx[n4 + tid]], 1u);
}

__global__ void sum_kernel(const float* __restrict__ sc, const unsigned* __restrict__ hist,
                           int K, double* __restrict__ accums) {
    int i = blockIdx.x * blockDim.x + threadIdx.x;
    int stride = gridDim.x * blockDim.x;
    double s = 0.0;
    for (int k = i; k < K; k += stride)
        s += (double)sc[k] + (double)hist[k] + 1e-8;
    double t = block_reduce_double(s);
    if (threadIdx.x == 0) atomicAdd(&accums[0], t);
}

extern "C" void kernel_launch(void* const* d_in, const int* in_sizes, int n_in,
                              void* d_out, int out_size, void* d_ws, size_t ws_size,
                              hipStream_t stream) {
    const int*   indices = (const int*)d_in[0];
    const float* sc      = (const float*)d_in[1];
    long long n = (long long)in_sizes[0];   // B*T = 16,777,216
    int K = in_sizes[1];                    // 65536
    float* out = (float*)d_out;

    const int nb = 256;
    const size_t W = (size_t)K >> 1;
    size_t need = (size_t)nb * W * 4 + (size_t)K * 4 + 256 + 32;
    bool fast = (ws_size >= need) && (K % 256 == 0) && (K <= 65536);

    if (fast) {
        unsigned* partials = (unsigned*)d_ws;
        unsigned* hist = partials + (size_t)nb * W;
        size_t acc_off = (((size_t)nb * W * 4 + (size_t)K * 4) + 255) & ~(size_t)255;
        double* accums = (double*)((char*)d_ws + acc_off);

        const int NC4 = (int)(W >> 2);
        lds_hist_kernel<<<nb, 1024, 0, stream>>>(indices, n, partials, K, nb, accums);
        merge_sum_kernel<<<NC4 / 32, 256, 0, stream>>>(
            reinterpret_cast<const uint4e*>(partials), nb, NC4, sc, hist, accums);
        bits_finalize_kernel<<<64, 256, 0, stream>>>(sc, hist, K, accums, out, n);
    } else {
        unsigned* hist = (unsigned*)d_ws;
        size_t acc_off = ((size_t)K * 4 + 255) & ~(size_t)255;
        double* accums = (double*)((char*)d_ws + acc_off);

        zero_kernel<<<256, 256, 0, stream>>>(hist, K, accums);
        ghist_kernel<<<2048, 256, 0, stream>>>(indices, n, hist);
        sum_kernel<<<256, 256, 0, stream>>>(sc, hist, K, accums);
        bits_finalize_kernel<<<64, 256, 0, stream>>>(sc, hist, K, accums, out, n);
    }
}